// Round 15
// baseline (190.418 us; speedup 1.0000x reference)
//
#include <hip/hip_runtime.h>
#include <hip/hip_bf16.h>
#include <math.h>

// GNNAngle round 15: R13 (best) + persistent blocks + cross-chunk prefetch
// kept alive across barriers via RAW s_barrier (no __syncthreads -> no
// compiler vmcnt(0) drain; T3/T4 technique, verified in the 8-phase GEMM
// template). Per iteration: wait prefetch -> cvt -> issue next chunk's 16
// loads -> Gram MFMA -> acos/scatter -> {lgkmcnt(0)+s_barrier} x4 through
// the MFMA MLP. Prefetch rides in flight under phase B: continuous HBM
// stream instead of burst-convoy (R11's idea, executed without the drain).

#define NTHREADS 256    // 4 waves
#define CHUNK    32     // nodes per chunk
#define ASTRIDE  136    // f16 act row stride (b128 conflict-free in MLP)
#define PBLOCKS  768    // 3 per CU

typedef _Float16 f16;
typedef f16  f16x8 __attribute__((ext_vector_type(8)));
typedef f16  f16x4 __attribute__((ext_vector_type(4)));
typedef float f32x4 __attribute__((ext_vector_type(4)));

__device__ __forceinline__ float fast_tanh(float x) {
    float e = __expf(2.0f * x);
    return 1.0f - 2.0f * __builtin_amdgcn_rcpf(e + 1.0f);
}

__device__ __forceinline__ float fast_acos(float x) {
    // Abramowitz-Stegun 4.4.45: max abs error 6.7e-5 rad, branchless
    float ax = fabsf(x);
    float p = fmaf(-0.0187293f, ax, 0.0742610f);
    p = fmaf(p, ax, -0.2121144f);
    p = fmaf(p, ax, 1.5707288f);
    float r = sqrtf(1.0f - ax) * p;
    return (x >= 0.0f) ? r : (3.14159265358979f - r);
}

// LDS-visibility fence + block barrier WITHOUT vmcnt drain (T3/T4):
// lgkmcnt(0) makes this wave's ds_writes land, raw s_barrier syncs waves,
// sched_barrier pins ordering (rule #18). Global loads stay in flight.
__device__ __forceinline__ void lds_barrier() {
    asm volatile("s_waitcnt lgkmcnt(0)" ::: "memory");
    __builtin_amdgcn_s_barrier();
    __builtin_amdgcn_sched_barrier(0);
}

// ---- prep: W[i][j] (f32 [IN][128]) -> Wt[j][i] f16 [128][128], K zero-padded
__global__ void prep_weights(const float* __restrict__ W1,
                             const float* __restrict__ W2,
                             const float* __restrict__ W3,
                             f16* __restrict__ wt)
{
    int tid = blockIdx.x * 256 + threadIdx.x;
    if (tid >= 3 * 128 * 128) return;
    int layer = tid >> 14;
    int rem   = tid & 16383;
    int j     = rem >> 7;
    int i     = rem & 127;
    const float* W = (layer == 0) ? W1 : ((layer == 1) ? W2 : W3);
    int in_l = (layer == 0) ? 120 : 128;
    float v = (i < in_l) ? W[i * 128 + j] : 0.0f;
    wt[tid] = (f16)v;   // wt[layer][j][i]
}

// one MLP layer: dst[node][j] = tanh(sum_i src[node][i]*W[i][j] + b[j])
__device__ __forceinline__ void mlp_layer_mfma(const f16* __restrict__ wl,   // [128][128] f16 ([j][i])
                                               const float* __restrict__ bias,
                                               const f16* src, f16* dst,     // LDS, stride ASTRIDE
                                               int w, int lr, int lg)
{
    #pragma unroll
    for (int jj = 0; jj < 2; ++jj) {
        const int jt = w * 2 + jj;
        const f16* wr = wl + (jt * 16 + lr) * 128 + lg * 8;
        f16x8 a0 = *(const f16x8*)(wr);
        f16x8 a1 = *(const f16x8*)(wr + 32);
        f16x8 a2 = *(const f16x8*)(wr + 64);
        f16x8 a3 = *(const f16x8*)(wr + 96);
        f32x4 bv = *(const f32x4*)(bias + jt * 16 + lg * 4);
        #pragma unroll
        for (int nt = 0; nt < 2; ++nt) {
            const int node = nt * 16 + lr;
            const f16* sr = src + node * ASTRIDE + lg * 8;
            f16x8 bf0 = *(const f16x8*)(sr);
            f16x8 bf1 = *(const f16x8*)(sr + 32);
            f16x8 bf2 = *(const f16x8*)(sr + 64);
            f16x8 bf3 = *(const f16x8*)(sr + 96);
            f32x4 acc = {0.f, 0.f, 0.f, 0.f};
            acc = __builtin_amdgcn_mfma_f32_16x16x32_f16(a0, bf0, acc, 0, 0, 0);
            acc = __builtin_amdgcn_mfma_f32_16x16x32_f16(a1, bf1, acc, 0, 0, 0);
            acc = __builtin_amdgcn_mfma_f32_16x16x32_f16(a2, bf2, acc, 0, 0, 0);
            acc = __builtin_amdgcn_mfma_f32_16x16x32_f16(a3, bf3, acc, 0, 0, 0);
            f16x4 o;
            #pragma unroll
            for (int r = 0; r < 4; ++r)
                o[r] = (f16)fast_tanh(acc[r] + bv[r]);
            *(f16x4*)(dst + node * ASTRIDE + jt * 16 + lg * 4) = o;
        }
    }
}

__global__ __launch_bounds__(NTHREADS, 3)
void gnn_persist(const float* __restrict__ edge_attr,
                 const f16*   __restrict__ wt,     // 3x[128][128] f16
                 const float* __restrict__ b1, const float* __restrict__ b2,
                 const float* __restrict__ b3,
                 const float* __restrict__ W4, const float* __restrict__ b4,
                 float* __restrict__ out, int n_nodes, int nchunks)
{
    __shared__ __attribute__((aligned(16))) f16   actA[CHUNK * ASTRIDE];
    __shared__ __attribute__((aligned(16))) f16   actB[CHUNK * ASTRIDE];
    __shared__ __attribute__((aligned(16))) float diag[4][8][16];   // rsq of Gram diag

    const int t = threadIdx.x;
    const int w = t >> 6;    // wave 0..3
    const int l = t & 63;
    const int lr = l & 15;
    const int lg = l >> 4;

    // K-pad cols 120..127 once; W1's rows 120..127 are zero anyway, so stale
    // values in later iterations are harmless (x * 0 == 0 for finite x).
    actA[(t >> 3) * ASTRIDE + 120 + (t & 7)] = (f16)0.f;

    // wave w owns nodes m = 4c + w, c = 0..7 of each chunk
    #define LOAD16(ch)                                                          \
        {                                                                       \
            const long b_ = (long)(ch) * CHUNK + w;                             \
            const float* sw_ = edge_attr + b_ * 512 + lr * 32 + lg * 8;         \
            _Pragma("unroll")                                                   \
            for (int c_ = 0; c_ < 8; ++c_) {                                    \
                float4 ta = make_float4(0.f,0.f,0.f,0.f), tb = ta;              \
                if (b_ + 4 * c_ < n_nodes) {                                    \
                    ta = *(const float4*)(sw_ + c_ * 2048);                     \
                    tb = *(const float4*)(sw_ + c_ * 2048 + 4);                 \
                }                                                               \
                da[c_] = ta; db[c_] = tb;                                       \
            }                                                                   \
        }

    long chunk = blockIdx.x;
    float4 da[8], db[8];
    LOAD16(chunk);                                  // initial issue

    for (; chunk < nchunks; chunk += PBLOCKS) {
        // ---- wait on prefetched raw data ----
        asm volatile("s_waitcnt vmcnt(0)" ::: "memory");
        __builtin_amdgcn_sched_barrier(0);

        // ---- cvt to f16 frags (frees raw regs for next prefetch) ----
        f16x8 f0, f1, f2, f3, f4, f5, f6, f7;
        #define CVT(fc, c)                                                      \
            fc[0]=(f16)da[c].x; fc[1]=(f16)da[c].y;                             \
            fc[2]=(f16)da[c].z; fc[3]=(f16)da[c].w;                             \
            fc[4]=(f16)db[c].x; fc[5]=(f16)db[c].y;                             \
            fc[6]=(f16)db[c].z; fc[7]=(f16)db[c].w;
        CVT(f0,0) CVT(f1,1) CVT(f2,2) CVT(f3,3)
        CVT(f4,4) CVT(f5,5) CVT(f6,6) CVT(f7,7)
        #undef CVT

        // ---- issue next chunk's 16 loads; they ride under phase B ----
        const long nxt = chunk + PBLOCKS;
        if (nxt < nchunks) LOAD16(nxt);

        // ---- 8 independent Gram MFMAs ----
        f32x4 g0,g1,g2,g3,g4,g5,g6,g7;
        {
            f32x4 z = {0.f,0.f,0.f,0.f};
            g0 = __builtin_amdgcn_mfma_f32_16x16x32_f16(f0, f0, z, 0,0,0);
            g1 = __builtin_amdgcn_mfma_f32_16x16x32_f16(f1, f1, z, 0,0,0);
            g2 = __builtin_amdgcn_mfma_f32_16x16x32_f16(f2, f2, z, 0,0,0);
            g3 = __builtin_amdgcn_mfma_f32_16x16x32_f16(f3, f3, z, 0,0,0);
            g4 = __builtin_amdgcn_mfma_f32_16x16x32_f16(f4, f4, z, 0,0,0);
            g5 = __builtin_amdgcn_mfma_f32_16x16x32_f16(f5, f5, z, 0,0,0);
            g6 = __builtin_amdgcn_mfma_f32_16x16x32_f16(f6, f6, z, 0,0,0);
            g7 = __builtin_amdgcn_mfma_f32_16x16x32_f16(f7, f7, z, 0,0,0);
        }

        // ---- 16 diag lanes write rsq(G[ii]); one wave-local fence ----
        if (lg == (lr >> 2)) {
            const int r = lr & 3;
            diag[w][0][lr] = __builtin_amdgcn_rsqf(g0[r] + 1e-24f);
            diag[w][1][lr] = __builtin_amdgcn_rsqf(g1[r] + 1e-24f);
            diag[w][2][lr] = __builtin_amdgcn_rsqf(g2[r] + 1e-24f);
            diag[w][3][lr] = __builtin_amdgcn_rsqf(g3[r] + 1e-24f);
            diag[w][4][lr] = __builtin_amdgcn_rsqf(g4[r] + 1e-24f);
            diag[w][5][lr] = __builtin_amdgcn_rsqf(g5[r] + 1e-24f);
            diag[w][6][lr] = __builtin_amdgcn_rsqf(g6[r] + 1e-24f);
            diag[w][7][lr] = __builtin_amdgcn_rsqf(g7[r] + 1e-24f);
        }
        asm volatile("s_waitcnt lgkmcnt(0)" ::: "memory");
        __builtin_amdgcn_sched_barrier(0);

        // ---- normalize + acos + scatter ----
        #define FIN(gc, c)                                                      \
            {                                                                   \
                const float rc = diag[w][c][lr];                                \
                const f32x4 rr = *(const f32x4*)&diag[w][c][lg * 4];            \
                const int m = (c) * 4 + w;                                      \
                const int col = lr;                                             \
                _Pragma("unroll")                                               \
                for (int r2 = 0; r2 < 4; ++r2) {                                \
                    const int row = lg * 4 + r2;                                \
                    float cv = gc[r2] * rr[r2] * rc;                            \
                    cv = fminf(fmaxf(cv, -1.0f + 1e-7f), 1.0f - 1e-7f);         \
                    float ang = fast_acos(cv);                                  \
                    if (row < col) {                                            \
                        const int p = 15*row - ((row*(row-1))>>1) + (col-row-1);\
                        actA[m * ASTRIDE + p] = (f16)ang;                       \
                    }                                                           \
                }                                                               \
            }
        FIN(g0,0) FIN(g1,1) FIN(g2,2) FIN(g3,3)
        FIN(g4,4) FIN(g5,5) FIN(g6,6) FIN(g7,7)
        #undef FIN

        lds_barrier();   // actA visible; prefetch loads stay in flight

        // ---- phase B: MLP on MFMA (raw barriers, no vmcnt drain) ----
        mlp_layer_mfma(wt,             b1, actA, actB, w, lr, lg);
        lds_barrier();
        mlp_layer_mfma(wt + 16384,     b2, actB, actA, w, lr, lg);
        lds_barrier();
        mlp_layer_mfma(wt + 2 * 16384, b3, actA, actB, w, lr, lg);
        lds_barrier();

        // ---- final 128->1 + sigmoid: 8 threads per node ----
        {
            const int node = t >> 3;       // 0..31
            const int part = t & 7;        // 0..7
            const int i0 = part * 16;
            const f16* sr = actB + node * ASTRIDE + i0;
            f16x8 h0 = *(const f16x8*)(sr);
            f16x8 h1 = *(const f16x8*)(sr + 8);
            float s = 0.f;
            #pragma unroll
            for (int e = 0; e < 8; ++e) s = fmaf((float)h0[e], W4[i0 + e], s);
            #pragma unroll
            for (int e = 0; e < 8; ++e) s = fmaf((float)h1[e], W4[i0 + 8 + e], s);
            s += __shfl_xor(s, 1);
            s += __shfl_xor(s, 2);
            s += __shfl_xor(s, 4);
            if (part == 0) {
                const long g = chunk * CHUNK + node;
                if (g < n_nodes)
                    out[g] = __builtin_amdgcn_rcpf(1.0f + __expf(-(s + b4[0])));
            }
        }
        // no trailing barrier: next iteration's post-FIN lds_barrier separates
        // this final's actB reads from the next layer-1 actB writes.
    }
    #undef LOAD16
}

extern "C" void kernel_launch(void* const* d_in, const int* in_sizes, int n_in,
                              void* d_out, int out_size, void* d_ws, size_t ws_size,
                              hipStream_t stream) {
    // inputs: 0:x 1:edge_index 2:edge_attr 3:k 4:W1 5:b1 6:W2 7:b2 8:W3 9:b3 10:W4 11:b4
    const float* edge_attr = (const float*)d_in[2];
    const float* W1 = (const float*)d_in[4];
    const float* b1 = (const float*)d_in[5];
    const float* W2 = (const float*)d_in[6];
    const float* b2 = (const float*)d_in[7];
    const float* W3 = (const float*)d_in[8];
    const float* b3 = (const float*)d_in[9];
    const float* W4 = (const float*)d_in[10];
    const float* b4 = (const float*)d_in[11];
    float* out = (float*)d_out;
    f16* wt = (f16*)d_ws;                        // 3*128*128 f16 = 96 KB

    const int n_nodes = in_sizes[2] / 512;       // E*D / (16*32)
    const int nchunks = (n_nodes + CHUNK - 1) / CHUNK;
    const int blocks  = PBLOCKS < nchunks ? PBLOCKS : nchunks;

    prep_weights<<<(3 * 128 * 128 + 255) / 256, 256, 0, stream>>>(W1, W2, W3, wt);

    gnn_persist<<<blocks, NTHREADS, 0, stream>>>(
        edge_attr, wt, b1, b2, b3, W4, b4, out, n_nodes, nchunks);
}

// Round 16
// 149.837 us; speedup vs baseline: 1.2708x; 1.2708x over previous
//
#include <hip/hip_runtime.h>
#include <hip/hip_bf16.h>
#include <math.h>

// GNNAngle round 16: unbundle R14. Keep cvt-as-loads-arrive (low VGPR peak
// ~100-110) but relax the cap: launch_bounds(256,4) -> <=128 VGPR, no spills,
// 4 blocks/CU (LDS 37KB*4=148KB fits) = 16 waves/CU vs R13's 12. Pure
// occupancy test on the flattened R13 structure (R5's null was on the old
// serial-chain structure; R14's regression was the too-tight 102-VGPR cap).

#define NTHREADS 256    // 4 waves
#define CHUNK    32     // nodes per block
#define ASTRIDE  136    // f16 act row stride (b128 conflict-free in MLP)

typedef _Float16 f16;
typedef f16  f16x8 __attribute__((ext_vector_type(8)));
typedef f16  f16x4 __attribute__((ext_vector_type(4)));
typedef float f32x4 __attribute__((ext_vector_type(4)));

__device__ __forceinline__ float fast_tanh(float x) {
    float e = __expf(2.0f * x);
    return 1.0f - 2.0f * __builtin_amdgcn_rcpf(e + 1.0f);
}

__device__ __forceinline__ float fast_acos(float x) {
    // Abramowitz-Stegun 4.4.45: max abs error 6.7e-5 rad, branchless
    float ax = fabsf(x);
    float p = fmaf(-0.0187293f, ax, 0.0742610f);
    p = fmaf(p, ax, -0.2121144f);
    p = fmaf(p, ax, 1.5707288f);
    float r = sqrtf(1.0f - ax) * p;
    return (x >= 0.0f) ? r : (3.14159265358979f - r);
}

// ---- prep: W[i][j] (f32 [IN][128]) -> Wt[j][i] f16 [128][128], K zero-padded
__global__ void prep_weights(const float* __restrict__ W1,
                             const float* __restrict__ W2,
                             const float* __restrict__ W3,
                             f16* __restrict__ wt)
{
    int tid = blockIdx.x * 256 + threadIdx.x;
    if (tid >= 3 * 128 * 128) return;
    int layer = tid >> 14;
    int rem   = tid & 16383;
    int j     = rem >> 7;
    int i     = rem & 127;
    const float* W = (layer == 0) ? W1 : ((layer == 1) ? W2 : W3);
    int in_l = (layer == 0) ? 120 : 128;
    float v = (i < in_l) ? W[i * 128 + j] : 0.0f;
    wt[tid] = (f16)v;   // wt[layer][j][i]
}

// one MLP layer: dst[node][j] = tanh(sum_i src[node][i]*W[i][j] + b[j])
__device__ __forceinline__ void mlp_layer_mfma(const f16* __restrict__ wl,   // [128][128] f16 ([j][i])
                                               const float* __restrict__ bias,
                                               const f16* src, f16* dst,     // LDS, stride ASTRIDE
                                               int w, int lr, int lg)
{
    #pragma unroll
    for (int jj = 0; jj < 2; ++jj) {
        const int jt = w * 2 + jj;
        const f16* wr = wl + (jt * 16 + lr) * 128 + lg * 8;
        f16x8 a0 = *(const f16x8*)(wr);
        f16x8 a1 = *(const f16x8*)(wr + 32);
        f16x8 a2 = *(const f16x8*)(wr + 64);
        f16x8 a3 = *(const f16x8*)(wr + 96);
        f32x4 bv = *(const f32x4*)(bias + jt * 16 + lg * 4);
        #pragma unroll
        for (int nt = 0; nt < 2; ++nt) {
            const int node = nt * 16 + lr;
            const f16* sr = src + node * ASTRIDE + lg * 8;
            f16x8 bf0 = *(const f16x8*)(sr);
            f16x8 bf1 = *(const f16x8*)(sr + 32);
            f16x8 bf2 = *(const f16x8*)(sr + 64);
            f16x8 bf3 = *(const f16x8*)(sr + 96);
            f32x4 acc = {0.f, 0.f, 0.f, 0.f};
            acc = __builtin_amdgcn_mfma_f32_16x16x32_f16(a0, bf0, acc, 0, 0, 0);
            acc = __builtin_amdgcn_mfma_f32_16x16x32_f16(a1, bf1, acc, 0, 0, 0);
            acc = __builtin_amdgcn_mfma_f32_16x16x32_f16(a2, bf2, acc, 0, 0, 0);
            acc = __builtin_amdgcn_mfma_f32_16x16x32_f16(a3, bf3, acc, 0, 0, 0);
            f16x4 o;
            #pragma unroll
            for (int r = 0; r < 4; ++r)
                o[r] = (f16)fast_tanh(acc[r] + bv[r]);
            *(f16x4*)(dst + node * ASTRIDE + jt * 16 + lg * 4) = o;
        }
    }
}

__global__ __launch_bounds__(NTHREADS, 4)
void gnn_angle_fused(const float* __restrict__ edge_attr,
                     const f16*   __restrict__ wt,     // 3x[128][128] f16
                     const float* __restrict__ b1, const float* __restrict__ b2,
                     const float* __restrict__ b3,
                     const float* __restrict__ W4, const float* __restrict__ b4,
                     float* __restrict__ out, int n_nodes)
{
    __shared__ __attribute__((aligned(16))) f16   actA[CHUNK * ASTRIDE];
    __shared__ __attribute__((aligned(16))) f16   actB[CHUNK * ASTRIDE];
    __shared__ __attribute__((aligned(16))) float diag[4][8][16];   // rsq of Gram diag, 2 KB

    const int t = threadIdx.x;
    const int w = t >> 6;    // wave 0..3
    const int l = t & 63;
    const int base = blockIdx.x * CHUNK;
    const int lr = l & 15;
    const int lg = l >> 4;

    // K-pad feats 120..127 for all 32 rows, once
    actA[(t >> 3) * ASTRIDE + 120 + (t & 7)] = (f16)0.f;

    // wave w owns nodes m = 4c + w, c = 0..7; lane holds row lr, dims lg*8..+8
    const float* sw = edge_attr + ((long)base + w) * 512 + lr * 32 + lg * 8;

    // ---- load all 8 nodes; cvt to f16 frag AS EACH ARRIVES (4 VGPR/node) ----
    f16x8 f0, f1, f2, f3, f4, f5, f6, f7;
    #define CVT(fc, c)                                                         \
        {                                                                      \
            float4 da = make_float4(0.f,0.f,0.f,0.f), db = da;                 \
            if (full || (long)base + 4*(c) + w < n_nodes) {                    \
                da = *(const float4*)(sw + (c) * 2048);                        \
                db = *(const float4*)(sw + (c) * 2048 + 4);                    \
            }                                                                  \
            fc[0]=(f16)da.x; fc[1]=(f16)da.y; fc[2]=(f16)da.z; fc[3]=(f16)da.w;\
            fc[4]=(f16)db.x; fc[5]=(f16)db.y; fc[6]=(f16)db.z; fc[7]=(f16)db.w;\
        }
    {
        const bool full = (base + CHUNK <= n_nodes);
        CVT(f0,0) CVT(f1,1) CVT(f2,2) CVT(f3,3)
        CVT(f4,4) CVT(f5,5) CVT(f6,6) CVT(f7,7)
    }
    #undef CVT

    // ---- 8 independent Gram MFMAs ----
    f32x4 g0,g1,g2,g3,g4,g5,g6,g7;
    {
        f32x4 z = {0.f,0.f,0.f,0.f};
        g0 = __builtin_amdgcn_mfma_f32_16x16x32_f16(f0, f0, z, 0,0,0);
        g1 = __builtin_amdgcn_mfma_f32_16x16x32_f16(f1, f1, z, 0,0,0);
        g2 = __builtin_amdgcn_mfma_f32_16x16x32_f16(f2, f2, z, 0,0,0);
        g3 = __builtin_amdgcn_mfma_f32_16x16x32_f16(f3, f3, z, 0,0,0);
        g4 = __builtin_amdgcn_mfma_f32_16x16x32_f16(f4, f4, z, 0,0,0);
        g5 = __builtin_amdgcn_mfma_f32_16x16x32_f16(f5, f5, z, 0,0,0);
        g6 = __builtin_amdgcn_mfma_f32_16x16x32_f16(f6, f6, z, 0,0,0);
        g7 = __builtin_amdgcn_mfma_f32_16x16x32_f16(f7, f7, z, 0,0,0);
    }

    // ---- 16 diag lanes write rsq(G[ii]); ONE fence for all 8 nodes ----
    if (lg == (lr >> 2)) {
        const int r = lr & 3;
        diag[w][0][lr] = __builtin_amdgcn_rsqf(g0[r] + 1e-24f);
        diag[w][1][lr] = __builtin_amdgcn_rsqf(g1[r] + 1e-24f);
        diag[w][2][lr] = __builtin_amdgcn_rsqf(g2[r] + 1e-24f);
        diag[w][3][lr] = __builtin_amdgcn_rsqf(g3[r] + 1e-24f);
        diag[w][4][lr] = __builtin_amdgcn_rsqf(g4[r] + 1e-24f);
        diag[w][5][lr] = __builtin_amdgcn_rsqf(g5[r] + 1e-24f);
        diag[w][6][lr] = __builtin_amdgcn_rsqf(g6[r] + 1e-24f);
        diag[w][7][lr] = __builtin_amdgcn_rsqf(g7[r] + 1e-24f);
    }
    asm volatile("s_waitcnt lgkmcnt(0)" ::: "memory");
    __builtin_amdgcn_sched_barrier(0);

    // ---- normalize + acos + scatter (independent per node) ----
    #define FIN(gc, c)                                                     \
        {                                                                  \
            const float rc = diag[w][c][lr];                               \
            const f32x4 rr = *(const f32x4*)&diag[w][c][lg * 4];           \
            const int m = (c) * 4 + w;                                     \
            const int col = lr;                                            \
            _Pragma("unroll")                                              \
            for (int r2 = 0; r2 < 4; ++r2) {                               \
                const int row = lg * 4 + r2;                               \
                float cv = gc[r2] * rr[r2] * rc;                           \
                cv = fminf(fmaxf(cv, -1.0f + 1e-7f), 1.0f - 1e-7f);        \
                float ang = fast_acos(cv);                                 \
                if (row < col) {                                           \
                    const int p = 15*row - ((row*(row-1))>>1) + (col-row-1); \
                    actA[m * ASTRIDE + p] = (f16)ang;                      \
                }                                                          \
            }                                                              \
        }
    FIN(g0,0) FIN(g1,1) FIN(g2,2) FIN(g3,3)
    FIN(g4,4) FIN(g5,5) FIN(g6,6) FIN(g7,7)
    #undef FIN
    __syncthreads();

    // ---------------- Phase B: MLP on MFMA ----------------
    mlp_layer_mfma(wt,             b1, actA, actB, w, lr, lg);
    __syncthreads();
    mlp_layer_mfma(wt + 16384,     b2, actB, actA, w, lr, lg);
    __syncthreads();
    mlp_layer_mfma(wt + 2 * 16384, b3, actA, actB, w, lr, lg);
    __syncthreads();

    // ---------------- final 128->1 + sigmoid: 8 threads per node ----------------
    {
        const int node = t >> 3;       // 0..31
        const int part = t & 7;        // 0..7
        const int i0 = part * 16;
        const f16* sr = actB + node * ASTRIDE + i0;
        f16x8 h0 = *(const f16x8*)(sr);
        f16x8 h1 = *(const f16x8*)(sr + 8);
        float s = 0.f;
        #pragma unroll
        for (int e = 0; e < 8; ++e) s = fmaf((float)h0[e], W4[i0 + e], s);
        #pragma unroll
        for (int e = 0; e < 8; ++e) s = fmaf((float)h1[e], W4[i0 + 8 + e], s);
        s += __shfl_xor(s, 1);
        s += __shfl_xor(s, 2);
        s += __shfl_xor(s, 4);
        if (part == 0) {
            const long g = (long)base + node;
            if (g < n_nodes)
                out[g] = __builtin_amdgcn_rcpf(1.0f + __expf(-(s + b4[0])));
        }
    }
}

extern "C" void kernel_launch(void* const* d_in, const int* in_sizes, int n_in,
                              void* d_out, int out_size, void* d_ws, size_t ws_size,
                              hipStream_t stream) {
    // inputs: 0:x 1:edge_index 2:edge_attr 3:k 4:W1 5:b1 6:W2 7:b2 8:W3 9:b3 10:W4 11:b4
    const float* edge_attr = (const float*)d_in[2];
    const float* W1 = (const float*)d_in[4];
    const float* b1 = (const float*)d_in[5];
    const float* W2 = (const float*)d_in[6];
    const float* b2 = (const float*)d_in[7];
    const float* W3 = (const float*)d_in[8];
    const float* b3 = (const float*)d_in[9];
    const float* W4 = (const float*)d_in[10];
    const float* b4 = (const float*)d_in[11];
    float* out = (float*)d_out;
    f16* wt = (f16*)d_ws;                        // 3*128*128 f16 = 96 KB

    const int n_nodes = in_sizes[2] / 512;       // E*D / (16*32)

    prep_weights<<<(3 * 128 * 128 + 255) / 256, 256, 0, stream>>>(W1, W2, W3, wt);

    const int blocks = (n_nodes + CHUNK - 1) / CHUNK;
    gnn_angle_fused<<<blocks, NTHREADS, 0, stream>>>(
        edge_attr, wt, b1, b2, b3, W4, b4, out, n_nodes);
}

// Round 17
// 130.458 us; speedup vs baseline: 1.4596x; 1.1485x over previous
//
#include <hip/hip_runtime.h>
#include <hip/hip_bf16.h>
#include <math.h>

// GNNAngle round 17: persistent pipeline with ZERO-VGPR prefetch.
// - Cross-chunk prefetch via __builtin_amdgcn_global_load_lds (width 16) into a
//   double-buffered 2x32KB LDS staging area: no registers held across phase B
//   (the diagnosed killer of R10/R11/R15).
// - Source-swizzled staging (rule #21): linear LDS dest, global src XOR-permuted
//   within each 1KB window, fragment ds_read_b128 swizzled to conflict-free.
// - ALL weight fragments (24 x f16x8) + biases + W4 preloaded to registers
//   before the loop (loop-invariant) -> steady-state vmem = 8 staging + 1 store.
//   vmcnt(1) at loop top == "staging landed" (in-order retirement).
// - Raw s_barrier + lgkmcnt fences only; no __syncthreads -> no vmcnt drain.

#define NTHREADS 256    // 4 waves
#define CHUNK    16     // nodes per iteration per block
#define ASTRIDE  136    // f16 act row stride
#define PBLOCKS  512    // 2 per CU

typedef _Float16 f16;
typedef f16  f16x8 __attribute__((ext_vector_type(8)));
typedef f16  f16x4 __attribute__((ext_vector_type(4)));
typedef float f32x4 __attribute__((ext_vector_type(4)));

#define MFMA16(a, b, c) __builtin_amdgcn_mfma_f32_16x16x32_f16(a, b, c, 0, 0, 0)

__device__ __forceinline__ float fast_tanh(float x) {
    float e = __expf(2.0f * x);
    return 1.0f - 2.0f * __builtin_amdgcn_rcpf(e + 1.0f);
}

__device__ __forceinline__ float fast_acos(float x) {
    float ax = fabsf(x);
    float p = fmaf(-0.0187293f, ax, 0.0742610f);
    p = fmaf(p, ax, -0.2121144f);
    p = fmaf(p, ax, 1.5707288f);
    float r = sqrtf(1.0f - ax) * p;
    return (x >= 0.0f) ? r : (3.14159265358979f - r);
}

__device__ __forceinline__ void load_lds16(const float* g, float* l) {
    __builtin_amdgcn_global_load_lds(
        (__attribute__((address_space(1))) void*)(g),
        (__attribute__((address_space(3))) void*)(l), 16, 0, 0);
}

// ---- prep: W[i][j] (f32 [IN][128]) -> Wt[j][i] f16 [128][128], K zero-padded
__global__ void prep_weights(const float* __restrict__ W1,
                             const float* __restrict__ W2,
                             const float* __restrict__ W3,
                             f16* __restrict__ wt)
{
    int tid = blockIdx.x * 256 + threadIdx.x;
    if (tid >= 3 * 128 * 128) return;
    int layer = tid >> 14;
    int rem   = tid & 16383;
    int j     = rem >> 7;
    int i     = rem & 127;
    const float* W = (layer == 0) ? W1 : ((layer == 1) ? W2 : W3);
    int in_l = (layer == 0) ? 120 : 128;
    float v = (i < in_l) ? W[i * 128 + j] : 0.0f;
    wt[tid] = (f16)v;   // wt[layer][j][i]
}

__global__ __launch_bounds__(NTHREADS, 2)
void gnn_pipe(const float* __restrict__ edge_attr,
              const f16*   __restrict__ wt,
              const float* __restrict__ b1, const float* __restrict__ b2,
              const float* __restrict__ b3,
              const float* __restrict__ W4, const float* __restrict__ b4,
              float* __restrict__ out, int n_nodes, int nchunks)
{
    __shared__ __attribute__((aligned(16))) float stg[2][8192];     // 2 x 32 KB raw staging
    __shared__ __attribute__((aligned(16))) f16   actA[16 * ASTRIDE];
    __shared__ __attribute__((aligned(16))) f16   actB[16 * ASTRIDE];
    __shared__ __attribute__((aligned(16))) float diag[4][4][16];

    const int t  = threadIdx.x;
    const int w  = t >> 6;     // wave 0..3
    const int l  = t & 63;
    const int lr = l & 15;
    const int lg = l >> 4;

    // K-pad cols 120..127 once (W1 pad rows are zero; later stale finite values harmless)
    if (t < 128) actA[(t >> 3) * ASTRIDE + 120 + (t & 7)] = (f16)0.f;

    // ---- preload ALL weight fragments (loop-invariant; wave owns j-tiles 2w,2w+1) ----
    #define LW(L, jj, kt) (*(const f16x8*)(wt + (L) * 16384 + ((w * 2 + (jj)) * 16 + lr) * 128 + (kt) * 32 + lg * 8))
    const f16x8 W000 = LW(0,0,0), W001 = LW(0,0,1), W002 = LW(0,0,2), W003 = LW(0,0,3);
    const f16x8 W010 = LW(0,1,0), W011 = LW(0,1,1), W012 = LW(0,1,2), W013 = LW(0,1,3);
    const f16x8 W100 = LW(1,0,0), W101 = LW(1,0,1), W102 = LW(1,0,2), W103 = LW(1,0,3);
    const f16x8 W110 = LW(1,1,0), W111 = LW(1,1,1), W112 = LW(1,1,2), W113 = LW(1,1,3);
    const f16x8 W200 = LW(2,0,0), W201 = LW(2,0,1), W202 = LW(2,0,2), W203 = LW(2,0,3);
    const f16x8 W210 = LW(2,1,0), W211 = LW(2,1,1), W212 = LW(2,1,2), W213 = LW(2,1,3);
    #undef LW
    const f32x4 bva0 = *(const f32x4*)(b1 + (w * 2 + 0) * 16 + lg * 4);
    const f32x4 bva1 = *(const f32x4*)(b1 + (w * 2 + 1) * 16 + lg * 4);
    const f32x4 bvb0 = *(const f32x4*)(b2 + (w * 2 + 0) * 16 + lg * 4);
    const f32x4 bvb1 = *(const f32x4*)(b2 + (w * 2 + 1) * 16 + lg * 4);
    const f32x4 bvc0 = *(const f32x4*)(b3 + (w * 2 + 0) * 16 + lg * 4);
    const f32x4 bvc1 = *(const f32x4*)(b3 + (w * 2 + 1) * 16 + lg * 4);
    const int   fpart = t & 15;
    const f32x4 w4a = *(const f32x4*)(W4 + fpart * 8);
    const f32x4 w4b = *(const f32x4*)(W4 + fpart * 8 + 4);
    const float bb4 = b4[0];

    // per-lane swizzled source offset within each staged 1KB window (bijective, coalesced)
    const int swsrc = (l * 16) ^ ((l >> 3) << 4);

    // wave w stages/computes nodes [ch*16 + w*4, +4)
    #define STAGE(ch_, b_)                                                       \
        {                                                                        \
            const long n0_ = (long)(ch_) * CHUNK + w * 4;                        \
            _Pragma("unroll")                                                    \
            for (int i_ = 0; i_ < 8; ++i_) {                                     \
                long nd_ = n0_ + (i_ >> 1);                                      \
                if (nd_ >= n_nodes) nd_ = n_nodes - 1;                           \
                const float* gs_ = (const float*)((const char*)edge_attr         \
                                   + nd_ * 2048 + (i_ & 1) * 1024 + swsrc);      \
                load_lds16(gs_, &stg[b_][w * 2048 + i_ * 256]);                  \
            }                                                                    \
        }

    #define LBAR()                                                               \
        {                                                                        \
            asm volatile("s_waitcnt lgkmcnt(0)" ::: "memory");                   \
            __builtin_amdgcn_s_barrier();                                        \
            __builtin_amdgcn_sched_barrier(0);                                   \
        }

    #define LAYER(SRC, DST, Wa0, Wa1, Wa2, Wa3, Wb0, Wb1, Wb2, Wb3, BV0, BV1)   \
        {                                                                        \
            const f16* sr_ = SRC + lr * ASTRIDE + lg * 8;                        \
            f16x8 s0_ = *(const f16x8*)(sr_);                                    \
            f16x8 s1_ = *(const f16x8*)(sr_ + 32);                               \
            f16x8 s2_ = *(const f16x8*)(sr_ + 64);                               \
            f16x8 s3_ = *(const f16x8*)(sr_ + 96);                               \
            f32x4 a0_ = {0.f, 0.f, 0.f, 0.f}, a1_ = a0_;                         \
            a0_ = MFMA16(Wa0, s0_, a0_); a1_ = MFMA16(Wb0, s0_, a1_);            \
            a0_ = MFMA16(Wa1, s1_, a0_); a1_ = MFMA16(Wb1, s1_, a1_);            \
            a0_ = MFMA16(Wa2, s2_, a0_); a1_ = MFMA16(Wb2, s2_, a1_);            \
            a0_ = MFMA16(Wa3, s3_, a0_); a1_ = MFMA16(Wb3, s3_, a1_);            \
            f16x4 o0_, o1_;                                                      \
            _Pragma("unroll")                                                    \
            for (int r_ = 0; r_ < 4; ++r_) {                                     \
                o0_[r_] = (f16)fast_tanh(a0_[r_] + BV0[r_]);                     \
                o1_[r_] = (f16)fast_tanh(a1_[r_] + BV1[r_]);                     \
            }                                                                    \
            *(f16x4*)(DST + lr * ASTRIDE + (w * 2 + 0) * 16 + lg * 4) = o0_;     \
            *(f16x4*)(DST + lr * ASTRIDE + (w * 2 + 1) * 16 + lg * 4) = o1_;     \
        }

    long ch = blockIdx.x;
    STAGE(ch, 0);
    asm volatile("s_waitcnt vmcnt(0)" ::: "memory");
    __builtin_amdgcn_sched_barrier(0);

    int it = 0;
    for (; ch < nchunks; ch += PBLOCKS, ++it) {
        const int b = it & 1;
        if (it) {
            // staging(ch) issued last iter, only the out-store is younger:
            // vmcnt(1) + in-order retirement  ==>  staging complete.
            asm volatile("s_waitcnt vmcnt(1)" ::: "memory");
            __builtin_amdgcn_sched_barrier(0);
        }

        // ---- phase A: fragments from staged LDS (swizzled, conflict-free) ----
        const char* ws_ = (const char*)&stg[b][w * 2048];
        const int abase = lr * 128 + lg * 32;
        const int akey  = (lr & 7) << 4;
        f16x8 f0, f1, f2, f3;
        #define FRAG(fc, m_)                                                     \
            {                                                                    \
                float4 va = *(const float4*)(ws_ + (m_) * 2048 + (abase ^ akey));        \
                float4 vb = *(const float4*)(ws_ + (m_) * 2048 + ((abase + 16) ^ akey)); \
                fc[0]=(f16)va.x; fc[1]=(f16)va.y; fc[2]=(f16)va.z; fc[3]=(f16)va.w;      \
                fc[4]=(f16)vb.x; fc[5]=(f16)vb.y; fc[6]=(f16)vb.z; fc[7]=(f16)vb.w;      \
            }
        FRAG(f0, 0) FRAG(f1, 1) FRAG(f2, 2) FRAG(f3, 3)
        #undef FRAG

        // ---- issue next chunk's staging (zero VGPR; rides under the whole iter) ----
        const long nxt = ch + PBLOCKS;
        if (nxt < nchunks) STAGE(nxt, b ^ 1);

        // ---- Gram MFMAs + diag + acos -> actA ----
        f32x4 g0, g1, g2, g3;
        {
            f32x4 z = {0.f, 0.f, 0.f, 0.f};
            g0 = MFMA16(f0, f0, z); g1 = MFMA16(f1, f1, z);
            g2 = MFMA16(f2, f2, z); g3 = MFMA16(f3, f3, z);
        }
        if (lg == (lr >> 2)) {
            const int r = lr & 3;
            diag[w][0][lr] = __builtin_amdgcn_rsqf(g0[r] + 1e-24f);
            diag[w][1][lr] = __builtin_amdgcn_rsqf(g1[r] + 1e-24f);
            diag[w][2][lr] = __builtin_amdgcn_rsqf(g2[r] + 1e-24f);
            diag[w][3][lr] = __builtin_amdgcn_rsqf(g3[r] + 1e-24f);
        }
        asm volatile("s_waitcnt lgkmcnt(0)" ::: "memory");
        __builtin_amdgcn_sched_barrier(0);

        #define FIN(gc, c)                                                       \
            {                                                                    \
                const float rc = diag[w][c][lr];                                 \
                const f32x4 rr = *(const f32x4*)&diag[w][c][lg * 4];             \
                const int m_ = w * 4 + (c);                                      \
                const int col = lr;                                              \
                _Pragma("unroll")                                                \
                for (int r2 = 0; r2 < 4; ++r2) {                                 \
                    const int row = lg * 4 + r2;                                 \
                    float cv = gc[r2] * rr[r2] * rc;                             \
                    cv = fminf(fmaxf(cv, -1.0f + 1e-7f), 1.0f - 1e-7f);          \
                    float ang = fast_acos(cv);                                   \
                    if (row < col) {                                             \
                        const int p = 15*row - ((row*(row-1))>>1) + (col-row-1); \
                        actA[m_ * ASTRIDE + p] = (f16)ang;                       \
                    }                                                            \
                }                                                                \
            }
        FIN(g0, 0) FIN(g1, 1) FIN(g2, 2) FIN(g3, 3)
        #undef FIN

        LBAR();   // actA visible block-wide; staging stays in flight

        // ---- phase B: 3 MFMA layers, weights in registers, pure LDS ----
        LAYER(actA, actB, W000, W001, W002, W003, W010, W011, W012, W013, bva0, bva1);
        LBAR();
        LAYER(actB, actA, W100, W101, W102, W103, W110, W111, W112, W113, bvb0, bvb1);
        LBAR();
        LAYER(actA, actB, W200, W201, W202, W203, W210, W211, W212, W213, bvc0, bvc1);
        LBAR();

        // ---- final 128->1 + sigmoid: 16 threads per node ----
        {
            const int node_ = t >> 4;          // 0..15
            const f16* fs_ = actB + node_ * ASTRIDE + fpart * 8;
            f16x8 h_ = *(const f16x8*)(fs_);
            float s_ = 0.f;
            s_ = fmaf((float)h_[0], w4a[0], s_); s_ = fmaf((float)h_[1], w4a[1], s_);
            s_ = fmaf((float)h_[2], w4a[2], s_); s_ = fmaf((float)h_[3], w4a[3], s_);
            s_ = fmaf((float)h_[4], w4b[0], s_); s_ = fmaf((float)h_[5], w4b[1], s_);
            s_ = fmaf((float)h_[6], w4b[2], s_); s_ = fmaf((float)h_[7], w4b[3], s_);
            s_ += __shfl_xor(s_, 1);
            s_ += __shfl_xor(s_, 2);
            s_ += __shfl_xor(s_, 4);
            s_ += __shfl_xor(s_, 8);
            if (fpart == 0) {
                const long gn_ = ch * CHUNK + node_;
                if (gn_ < n_nodes)
                    out[gn_] = __builtin_amdgcn_rcpf(1.0f + __expf(-(s_ + bb4)));
            }
        }
        // no trailing barrier: next iter's FIN writes actA only after this
        // iter's post-L3 LBAR (all waves past their actA reads).
    }
    #undef STAGE
    #undef LBAR
    #undef LAYER
}

extern "C" void kernel_launch(void* const* d_in, const int* in_sizes, int n_in,
                              void* d_out, int out_size, void* d_ws, size_t ws_size,
                              hipStream_t stream) {
    // inputs: 0:x 1:edge_index 2:edge_attr 3:k 4:W1 5:b1 6:W2 7:b2 8:W3 9:b3 10:W4 11:b4
    const float* edge_attr = (const float*)d_in[2];
    const float* W1 = (const float*)d_in[4];
    const float* b1 = (const float*)d_in[5];
    const float* W2 = (const float*)d_in[6];
    const float* b2 = (const float*)d_in[7];
    const float* W3 = (const float*)d_in[8];
    const float* b3 = (const float*)d_in[9];
    const float* W4 = (const float*)d_in[10];
    const float* b4 = (const float*)d_in[11];
    float* out = (float*)d_out;
    f16* wt = (f16*)d_ws;                        // 3*128*128 f16 = 96 KB

    const int n_nodes = in_sizes[2] / 512;       // E*D / (16*32)
    const int nchunks = (n_nodes + CHUNK - 1) / CHUNK;
    const int blocks  = PBLOCKS < nchunks ? PBLOCKS : nchunks;

    prep_weights<<<(3 * 128 * 128 + 255) / 256, 256, 0, stream>>>(W1, W2, W3, wt);

    gnn_pipe<<<blocks, NTHREADS, 0, stream>>>(
        edge_attr, wt, b1, b2, b3, W4, b4, out, n_nodes, nchunks);
}